// Round 1
// baseline (1101.174 us; speedup 1.0000x reference)
//
#include <hip/hip_runtime.h>
#include <hip/hip_bf16.h>

typedef __attribute__((ext_vector_type(8))) short short8;
typedef __attribute__((ext_vector_type(4))) float floatx4;
typedef __attribute__((ext_vector_type(4))) int intx4;

#define M_TOT (64 * 4096)   // 262144 tokens
#define E_DIM 512
#define NTOK 256
#define KPAD 576            // 18 * 32
#define WT_ELEMS (NTOK * KPAD)

__device__ __forceinline__ unsigned short f2bf(float f) {
    unsigned u = __builtin_bit_cast(unsigned, f);
    u += 0x7FFFu + ((u >> 16) & 1u);   // round-to-nearest-even
    return (unsigned short)(u >> 16);
}

// Pack W transposed+padded to bf16: Wt[n][k], k<513 -> app_W[k][n],
// 513<=k<568 -> st_W[k-513][n], else 0. Also bias[n] = app_b[n]+st_b[n].
__global__ void prep_kernel(const float* __restrict__ app_W,
                            const float* __restrict__ app_b,
                            const float* __restrict__ st_W,
                            const float* __restrict__ st_b,
                            unsigned short* __restrict__ Wt,
                            float* __restrict__ bias) {
    int n = blockIdx.x;    // 0..255 output col
    int t = threadIdx.x;   // k part
    for (int k = t; k < KPAD; k += 256) {
        float v;
        if (k < 513)      v = app_W[(size_t)k * NTOK + n];
        else if (k < 568) v = st_W[(size_t)(k - 513) * NTOK + n];
        else              v = 0.0f;
        Wt[(size_t)n * KPAD + k] = f2bf(v);
    }
    if (t == 0) bias[n] = app_b[n] + st_b[n];
}

__device__ __forceinline__ float load_tail(const float* __restrict__ vis,
                                           const float* __restrict__ bbox,
                                           const float* __restrict__ kp,
                                           int token, int k) {
    // k in [512, 576)
    if (k == 512) return vis[token];
    if (k < 517)  return bbox[token * 4 + (k - 513)];
    if (k < 568)  return kp[token * 51 + (k - 517)];
    return 0.0f;
}

__global__ __launch_bounds__(256, 2)
void gemm_kernel(const float* __restrict__ emb, const float* __restrict__ vis,
                 const float* __restrict__ bbox, const float* __restrict__ kp,
                 const int* __restrict__ mask,
                 const unsigned short* __restrict__ Wt,
                 const float* __restrict__ bias,
                 float* __restrict__ out) {
    const int c_tile = blockIdx.x;   // 0..1   (col fastest: pair shares M-tile)
    const int m_tile = blockIdx.y;   // 0..2047
    const int tid  = threadIdx.x;
    const int lane = tid & 63;
    const int w    = tid >> 6;
    const int q    = lane >> 4;      // quad 0..3
    const int l16  = lane & 15;
    const int wr   = w >> 1, wc = w & 1;
    const int row0 = m_tile * 128 + wr * 64;   // wave's first token row
    const int col0 = c_tile * 128 + wc * 64;   // wave's first output col

    floatx4 acc[4][4] = {};   // [row-tile][col-tile], 64 VGPRs

    // ---- main K loop: chunks 0..15 are pure embeddings ----
    #pragma unroll 2
    for (int ch = 0; ch < 16; ++ch) {
        const int kb = ch * 32 + q * 8;
        short8 a[4];
        #pragma unroll
        for (int rt = 0; rt < 4; ++rt) {
            const float* p = emb + (size_t)(row0 + rt * 16 + l16) * E_DIM + kb;
            floatx4 x0 = *(const floatx4*)p;
            floatx4 x1 = *(const floatx4*)(p + 4);
            short8 v;
            v[0] = (short)f2bf(x0[0]); v[1] = (short)f2bf(x0[1]);
            v[2] = (short)f2bf(x0[2]); v[3] = (short)f2bf(x0[3]);
            v[4] = (short)f2bf(x1[0]); v[5] = (short)f2bf(x1[1]);
            v[6] = (short)f2bf(x1[2]); v[7] = (short)f2bf(x1[3]);
            a[rt] = v;
        }
        short8 b[4];
        #pragma unroll
        for (int ct = 0; ct < 4; ++ct) {
            const unsigned short* p = Wt + (size_t)(col0 + ct * 16 + l16) * KPAD + kb;
            b[ct] = *(const short8*)p;   // 16B load, L2-resident
        }
        #pragma unroll
        for (int rt = 0; rt < 4; ++rt)
            #pragma unroll
            for (int ct = 0; ct < 4; ++ct)
                acc[rt][ct] = __builtin_amdgcn_mfma_f32_16x16x32_bf16(
                    a[rt], b[ct], acc[rt][ct], 0, 0, 0);
    }

    // ---- tail chunks 16..17: vis/bbox/kp gather (quad-uniform k) ----
    #pragma unroll
    for (int ch = 16; ch < 18; ++ch) {
        const int kb = ch * 32 + q * 8;
        short8 a[4];
        #pragma unroll
        for (int rt = 0; rt < 4; ++rt) {
            int token = row0 + rt * 16 + l16;
            short8 v;
            #pragma unroll
            for (int j = 0; j < 8; ++j)
                v[j] = (short)f2bf(load_tail(vis, bbox, kp, token, kb + j));
            a[rt] = v;
        }
        short8 b[4];
        #pragma unroll
        for (int ct = 0; ct < 4; ++ct) {
            const unsigned short* p = Wt + (size_t)(col0 + ct * 16 + l16) * KPAD + kb;
            b[ct] = *(const short8*)p;
        }
        #pragma unroll
        for (int rt = 0; rt < 4; ++rt)
            #pragma unroll
            for (int ct = 0; ct < 4; ++ct)
                acc[rt][ct] = __builtin_amdgcn_mfma_f32_16x16x32_bf16(
                    a[rt], b[ct], acc[rt][ct], 0, 0, 0);
    }

    // ---- epilogue: C/D layout col=lane&15, row=quad*4+reg ----
    float bv[4];
    #pragma unroll
    for (int ct = 0; ct < 4; ++ct) bv[ct] = bias[col0 + ct * 16 + l16];

    #pragma unroll
    for (int rt = 0; rt < 4; ++rt) {
        intx4 mv = *(const intx4*)(mask + row0 + rt * 16 + q * 4);
        #pragma unroll
        for (int reg = 0; reg < 4; ++reg) {
            int r = row0 + rt * 16 + q * 4 + reg;
            float msc = mv[reg] ? 1.0f : 0.0f;
            #pragma unroll
            for (int ct = 0; ct < 4; ++ct) {
                int c = col0 + ct * 16 + l16;
                out[(size_t)r * NTOK + c] = (acc[rt][ct][reg] + bv[ct]) * msc;
            }
        }
    }
}

extern "C" void kernel_launch(void* const* d_in, const int* in_sizes, int n_in,
                              void* d_out, int out_size, void* d_ws, size_t ws_size,
                              hipStream_t stream) {
    const float* emb   = (const float*)d_in[0];
    const float* vis   = (const float*)d_in[1];
    const float* bbox  = (const float*)d_in[2];
    const float* kp    = (const float*)d_in[3];
    const int*   mask  = (const int*)d_in[4];
    const float* app_W = (const float*)d_in[5];
    const float* app_b = (const float*)d_in[6];
    const float* st_W  = (const float*)d_in[7];
    const float* st_b  = (const float*)d_in[8];

    unsigned short* Wt = (unsigned short*)d_ws;
    float* bias = (float*)((char*)d_ws + (size_t)WT_ELEMS * sizeof(unsigned short));
    float* out = (float*)d_out;

    hipLaunchKernelGGL(prep_kernel, dim3(NTOK), dim3(256), 0, stream,
                       app_W, app_b, st_W, st_b, Wt, bias);
    hipLaunchKernelGGL(gemm_kernel, dim3(2, 2048), dim3(256), 0, stream,
                       emb, vis, bbox, kp, mask, Wt, bias, out);
}

// Round 2
// 1093.688 us; speedup vs baseline: 1.0068x; 1.0068x over previous
//
#include <hip/hip_runtime.h>
#include <hip/hip_bf16.h>

typedef __attribute__((ext_vector_type(8))) short short8;
typedef __attribute__((ext_vector_type(4))) float floatx4;
typedef __attribute__((ext_vector_type(4))) int intx4;

#define E_DIM 512
#define NTOK 256
#define KPAD 576            // 18 * 32
#define WT_ELEMS (NTOK * KPAD)

__device__ __forceinline__ unsigned short f2bf(float f) {
    unsigned u = __builtin_bit_cast(unsigned, f);
    u += 0x7FFFu + ((u >> 16) & 1u);   // round-to-nearest-even
    return (unsigned short)(u >> 16);
}

__device__ __forceinline__ short8 cvt_frag(floatx4 x0, floatx4 x1) {
    short8 v;
    v[0] = (short)f2bf(x0[0]); v[1] = (short)f2bf(x0[1]);
    v[2] = (short)f2bf(x0[2]); v[3] = (short)f2bf(x0[3]);
    v[4] = (short)f2bf(x1[0]); v[5] = (short)f2bf(x1[1]);
    v[6] = (short)f2bf(x1[2]); v[7] = (short)f2bf(x1[3]);
    return v;
}

// Pack W transposed+padded to bf16: Wt[n][k]. Coalesced reads (thread = n).
__global__ void prep_kernel(const float* __restrict__ app_W,
                            const float* __restrict__ app_b,
                            const float* __restrict__ st_W,
                            const float* __restrict__ st_b,
                            unsigned short* __restrict__ Wt,
                            float* __restrict__ bias) {
    int n = threadIdx.x;          // 0..255 output col (coalesced on reads)
    int k0 = blockIdx.x * 4;      // 144 blocks x 4 k each = 576
    #pragma unroll
    for (int i = 0; i < 4; ++i) {
        int k = k0 + i;
        float v;
        if (k < 513)      v = app_W[(size_t)k * NTOK + n];
        else if (k < 568) v = st_W[(size_t)(k - 513) * NTOK + n];
        else              v = 0.0f;
        Wt[(size_t)n * KPAD + k] = f2bf(v);
    }
    if (blockIdx.x == 0) bias[n] = app_b[n] + st_b[n];
}

// Branchless-ish tail element fetch, k in [512, 576)
__device__ __forceinline__ float load_tail(const float* __restrict__ vis,
                                           const float* __restrict__ bbox,
                                           const float* __restrict__ kp,
                                           int token, int k) {
    float v = 0.0f;
    if (k < 568) {
        const float* base = (k < 513) ? vis : ((k < 517) ? bbox : kp);
        int off = (k < 513) ? token
                 : ((k < 517) ? (token * 4 + (k - 513))
                              : (token * 51 + (k - 517)));
        v = base[off];
    }
    return v;
}

__global__ __launch_bounds__(256, 2)
void gemm_kernel(const float* __restrict__ emb, const float* __restrict__ vis,
                 const float* __restrict__ bbox, const float* __restrict__ kp,
                 const int* __restrict__ mask,
                 const unsigned short* __restrict__ Wt,
                 const float* __restrict__ bias,
                 float* __restrict__ out) {
    const int c_tile = blockIdx.x;   // 0..1   (col fastest: pair shares A rows)
    const int m_tile = blockIdx.y;   // 0..2047
    const int tid  = threadIdx.x;
    const int lane = tid & 63;
    const int w    = tid >> 6;
    const int q    = lane >> 4;      // quad 0..3
    const int l16  = lane & 15;
    const int wr   = w >> 1, wc = w & 1;
    const int row0 = m_tile * 128 + wr * 64;
    const int col0 = c_tile * 128 + wc * 64;

    // Per-fragment base pointers (chunk offset added as immediate/induction)
    const float* aptr[4];
    #pragma unroll
    for (int rt = 0; rt < 4; ++rt)
        aptr[rt] = emb + (size_t)(row0 + rt * 16 + l16) * E_DIM + q * 8;
    const unsigned short* bptr[4];
    #pragma unroll
    for (int ct = 0; ct < 4; ++ct)
        bptr[ct] = Wt + (size_t)(col0 + ct * 16 + l16) * KPAD + q * 8;

    floatx4 acc[4][4] = {};   // 64 VGPRs
    floatx4 af[2][4][2];      // fp32 A double-buffer, 64 VGPRs
    short8  bf[2][4];         // B double-buffer, 32 VGPRs

    // ---- prologue: issue chunk 0 loads (B first, then A) ----
    #pragma unroll
    for (int ct = 0; ct < 4; ++ct) bf[0][ct] = *(const short8*)(bptr[ct]);
    #pragma unroll
    for (int rt = 0; rt < 4; ++rt) {
        af[0][rt][0] = *(const floatx4*)(aptr[rt]);
        af[0][rt][1] = *(const floatx4*)(aptr[rt] + 4);
    }

    // ---- main K loop, chunks 0..15 (pure embeddings), depth-1 prefetch ----
    #pragma unroll
    for (int ch = 0; ch < 16; ++ch) {
        const int cur = ch & 1, nxt = cur ^ 1;
        if (ch < 15) {
            const int off = (ch + 1) * 32;
            #pragma unroll
            for (int ct = 0; ct < 4; ++ct)
                bf[nxt][ct] = *(const short8*)(bptr[ct] + off);
            #pragma unroll
            for (int rt = 0; rt < 4; ++rt) {
                af[nxt][rt][0] = *(const floatx4*)(aptr[rt] + off);
                af[nxt][rt][1] = *(const floatx4*)(aptr[rt] + off + 4);
            }
        }
        short8 a[4];
        #pragma unroll
        for (int rt = 0; rt < 4; ++rt)
            a[rt] = cvt_frag(af[cur][rt][0], af[cur][rt][1]);
        #pragma unroll
        for (int rt = 0; rt < 4; ++rt)
            #pragma unroll
            for (int ct = 0; ct < 4; ++ct)
                acc[rt][ct] = __builtin_amdgcn_mfma_f32_16x16x32_bf16(
                    a[rt], bf[cur][ct], acc[rt][ct], 0, 0, 0);
    }

    // ---- tail chunks 16..17: vis/bbox/kp gather ----
    #pragma unroll
    for (int ch = 16; ch < 18; ++ch) {
        const int kb = ch * 32 + q * 8;
        const int off = ch * 32;
        short8 b2[4];
        #pragma unroll
        for (int ct = 0; ct < 4; ++ct)
            b2[ct] = *(const short8*)(bptr[ct] + off);
        float t[4][8];
        #pragma unroll
        for (int rt = 0; rt < 4; ++rt) {
            int token = row0 + rt * 16 + l16;
            #pragma unroll
            for (int j = 0; j < 8; ++j)
                t[rt][j] = load_tail(vis, bbox, kp, token, kb + j);
        }
        #pragma unroll
        for (int rt = 0; rt < 4; ++rt) {
            short8 a;
            #pragma unroll
            for (int j = 0; j < 8; ++j) a[j] = (short)f2bf(t[rt][j]);
            #pragma unroll
            for (int ct = 0; ct < 4; ++ct)
                acc[rt][ct] = __builtin_amdgcn_mfma_f32_16x16x32_bf16(
                    a, b2[ct], acc[rt][ct], 0, 0, 0);
        }
    }

    // ---- epilogue: C/D layout col=lane&15, row=quad*4+reg ----
    float bv[4];
    #pragma unroll
    for (int ct = 0; ct < 4; ++ct) bv[ct] = bias[col0 + ct * 16 + l16];

    #pragma unroll
    for (int rt = 0; rt < 4; ++rt) {
        intx4 mv = *(const intx4*)(mask + row0 + rt * 16 + q * 4);
        #pragma unroll
        for (int reg = 0; reg < 4; ++reg) {
            int r = row0 + rt * 16 + q * 4 + reg;
            float msc = mv[reg] ? 1.0f : 0.0f;
            #pragma unroll
            for (int ct = 0; ct < 4; ++ct) {
                int c = col0 + ct * 16 + l16;
                out[(size_t)r * NTOK + c] = (acc[rt][ct][reg] + bv[ct]) * msc;
            }
        }
    }
}

extern "C" void kernel_launch(void* const* d_in, const int* in_sizes, int n_in,
                              void* d_out, int out_size, void* d_ws, size_t ws_size,
                              hipStream_t stream) {
    const float* emb   = (const float*)d_in[0];
    const float* vis   = (const float*)d_in[1];
    const float* bbox  = (const float*)d_in[2];
    const float* kp    = (const float*)d_in[3];
    const int*   mask  = (const int*)d_in[4];
    const float* app_W = (const float*)d_in[5];
    const float* app_b = (const float*)d_in[6];
    const float* st_W  = (const float*)d_in[7];
    const float* st_b  = (const float*)d_in[8];

    unsigned short* Wt = (unsigned short*)d_ws;
    float* bias = (float*)((char*)d_ws + (size_t)WT_ELEMS * sizeof(unsigned short));
    float* out = (float*)d_out;

    hipLaunchKernelGGL(prep_kernel, dim3(144), dim3(256), 0, stream,
                       app_W, app_b, st_W, st_b, Wt, bias);
    hipLaunchKernelGGL(gemm_kernel, dim3(2, 2048), dim3(256), 0, stream,
                       emb, vis, bbox, kp, mask, Wt, bias, out);
}